// Round 15
// baseline (213.007 us; speedup 1.0000x reference)
//
#include <hip/hip_runtime.h>
#include <math.h>

#define NPOS 110592   // 48*48*48
#define EPS 1e-5f

using bf16x8 = __attribute__((ext_vector_type(8))) short;
using f32x4  = __attribute__((ext_vector_type(4))) float;
using f32x2  = __attribute__((ext_vector_type(2))) float;

// ws layout (float-slot offsets)
constexpr long O_WB    = 0;        // 112x128 bf16 = 7168 slots (W[oc][c])
constexpr long O_WPT   = 7168;     // 27*16 fp32 (wposT[o][k])
constexpr long O_SARR  = 7600;     // 96  (BN scale: 0..63 q, 64..95 v)
constexpr long O_TARR  = 7696;     // 96  (BN shift)
constexpr long O_RMAX  = 7792;     // 32  (softmax rowmax per (b,k))
constexpr long O_ZP    = 7824;     // 432*16 softmax denom partials
constexpr long O_RZI   = 14736;    // 32 (1/Z)
constexpr long O_SW    = 14768;    // 4*27*16 (s_q-folded conv weights)
constexpr long O_CW    = 16496;    // 108(+pad) (t_q-folded conv bias)
constexpr long O_LAMC  = 16608;    // 2*16*32 (unused scratch now)
constexpr long O_LAMC2 = 17632;    // 2*4*16*32 (s_q-folded lam_c)
constexpr long O_BC    = 21728;    // 2*4*32 (t_q-folded lam_c bias)
constexpr long O_LAMCP = 21984;    // 2*216*512 lam_c partials
constexpr long O_Q     = 243168;   // u32[2][32][NPOS] bf16-pairs
constexpr long O_K     = 7321056;  // f32[2][16][NPOS]
constexpr long O_V     = 10860000; // u32[2][16][NPOS] bf16-pairs
// total ~57.6 MB

__device__ inline unsigned short f2bf(float f) {
    unsigned int u = __float_as_uint(f);
    u += 0x7FFFu + ((u >> 16) & 1u);   // RNE
    return (unsigned short)(u >> 16);
}
__device__ inline float bflo(unsigned int u) { return __uint_as_float(u << 16); }
__device__ inline float bfhi(unsigned int u) { return __uint_as_float(u & 0xFFFF0000u); }
__device__ inline unsigned int cvtpk(float a, float b) {
    unsigned int r;
    asm("v_cvt_pk_bf16_f32 %0, %1, %2" : "=v"(r) : "v"(a), "v"(b));
    return r;
}
__device__ inline void pkfma(f32x2& c, f32x2 a, f32x2 b) {
    asm("v_pk_fma_f32 %0, %1, %2, %0" : "+v"(c) : "v"(a), "v"(b));
}

// DPP row reductions (VALU pipe, no LDS): lane 15 of each 16-lane row gets the result.
template<int CTRL>
__device__ inline float dpp_shr(float x) {
    int xi = __builtin_bit_cast(int, x);
    return __builtin_bit_cast(float, __builtin_amdgcn_update_dpp(xi, xi, CTRL, 0xf, 0xf, false));
}
__device__ inline float dpp_sum16(float x) {
    x += dpp_shr<0x111>(x);
    x += dpp_shr<0x112>(x);
    x += dpp_shr<0x114>(x);
    x += dpp_shr<0x118>(x);
    return x;
}
__device__ inline float dpp_max16(float x) {
    x = fmaxf(x, dpp_shr<0x111>(x));
    x = fmaxf(x, dpp_shr<0x112>(x));
    x = fmaxf(x, dpp_shr<0x114>(x));
    x = fmaxf(x, dpp_shr<0x118>(x));
    return x;
}

// ---------------- setup: bf16 weights [oc][c] + wposT ----------------
__global__ __launch_bounds__(256) void ksetup(const float* Wq, const float* Wk, const float* Wv,
                                              const float* Wpos, float* ws) {
    int i = blockIdx.x * 256 + threadIdx.x;
    if (i < 7168) {
        int oc = i >> 6, cp = i & 63;
        int c = 2 * cp;
        float v0, v1;
        if (oc < 64)      { v0 = Wq[oc * 128 + c];        v1 = Wq[oc * 128 + c + 1]; }
        else if (oc < 80) { v0 = Wk[(oc - 64) * 128 + c]; v1 = Wk[(oc - 64) * 128 + c + 1]; }
        else              { v0 = Wv[(oc - 80) * 128 + c]; v1 = Wv[(oc - 80) * 128 + c + 1]; }
        ((unsigned int*)(ws + O_WB))[i] = (unsigned int)f2bf(v0) | ((unsigned int)f2bf(v1) << 16);
    } else if (i < 7600) {
        int j = i - 7168;
        int o = j >> 4, k = j & 15;
        ws[O_WPT + j] = Wpos[k * 27 + o];   // o = od*9+oh*3+ow
    }
}

// ---------------- projection via MFMA + fused stat partials (DPP reduce) ----------------
// LDS 21.5 KB/block -> 7 blocks/CU; launch_bounds min-waves/EU = 7 to allow it
__global__ __launch_bounds__(256, 7) void kproj(const float* __restrict__ x, const float* __restrict__ ws,
                                                unsigned int* __restrict__ qu, float* __restrict__ kr,
                                                unsigned int* __restrict__ vu,
                                                float* __restrict__ PS, float* __restrict__ PQ,
                                                float* __restrict__ PM) {
    __shared__ unsigned int xsu[64 * 68];   // [pos][c-pair] bf16, row = 272 B (16B aligned)
    __shared__ float pss[4 * 112], psq[4 * 112], pmx[4 * 16];
    const unsigned short* WBu = (const unsigned short*)(ws + O_WB);

    int blk0 = blockIdx.x;                // XCD-aware bijective swizzle (grid 3456 = 8*432)
    int blk = (blk0 & 7) * 432 + (blk0 >> 3);
    int b = blk / 1728, tile = blk - b * 1728;
    long base = (long)b * 128 * NPOS + (long)tile * 64;
    int tid = threadIdx.x;

    // stage x tile transposed to [pos][c] bf16; b128 writes (4 iters)
    for (int i = tid; i < 1024; i += 256) {
        int cc = i >> 6, p = i & 63;      // cc: group of 8 channels
        const float* xp = x + base + (long)(8 * cc) * NPOS + p;
        uint4 w;
        w.x = cvtpk(xp[0],               xp[(long)NPOS]);
        w.y = cvtpk(xp[2 * (long)NPOS],  xp[3 * (long)NPOS]);
        w.z = cvtpk(xp[4 * (long)NPOS],  xp[5 * (long)NPOS]);
        w.w = cvtpk(xp[6 * (long)NPOS],  xp[7 * (long)NPOS]);
        *(uint4*)(xsu + p * 68 + cc * 4) = w;
    }
    __syncthreads();

    int lane = tid & 63;
    int wv = __builtin_amdgcn_readfirstlane(tid >> 6);
    int r = lane & 15, g = lane >> 4;

    f32x4 acc[7];
#pragma unroll
    for (int t = 0; t < 7; ++t) acc[t] = (f32x4){0.f, 0.f, 0.f, 0.f};

    const unsigned short* xrow = (const unsigned short*)xsu + (wv * 16 + r) * 136;
#pragma unroll
    for (int ks = 0; ks < 4; ++ks) {
        bf16x8 bfrag = *(const bf16x8*)(const void*)(xrow + ks * 32 + g * 8);
#pragma unroll
        for (int t = 0; t < 7; ++t) {
            bf16x8 afrag = *(const bf16x8*)(const void*)(WBu + (t * 16 + r) * 128 + ks * 32 + g * 8);
            acc[t] = __builtin_amdgcn_mfma_f32_16x16x32_bf16(afrag, bfrag, acc[t], 0, 0, 0);
        }
    }

    long pos = (long)tile * 64 + wv * 16 + r;
    // q (t 0..3): bf16-pair u32
#pragma unroll
    for (int t = 0; t < 4; ++t)
#pragma unroll
        for (int jp = 0; jp < 2; ++jp)
            qu[((long)b * 32 + t * 8 + g * 2 + jp) * NPOS + pos] = cvtpk(acc[t][2 * jp], acc[t][2 * jp + 1]);
    // k (t=4): fp32
#pragma unroll
    for (int j = 0; j < 4; ++j)
        kr[((long)b * 16 + g * 4 + j) * NPOS + pos] = acc[4][j];
    // v (t 5..6): bf16-pair u32
#pragma unroll
    for (int t = 5; t < 7; ++t)
#pragma unroll
        for (int jp = 0; jp < 2; ++jp)
            vu[((long)b * 16 + (t - 5) * 8 + g * 2 + jp) * NPOS + pos] = cvtpk(acc[t][2 * jp], acc[t][2 * jp + 1]);

    // fused stat partials via DPP (VALU pipe); row result lands in lane r==15
#pragma unroll
    for (int t = 0; t < 7; ++t) {
#pragma unroll
        for (int j = 0; j < 4; ++j) {
            float v = acc[t][j];
            float s = dpp_sum16(v);
            float q = dpp_sum16(v * v);
            if (r == 15) {
                int oc = t * 16 + g * 4 + j;
                pss[wv * 112 + oc] = s;
                psq[wv * 112 + oc] = q;
            }
        }
    }
#pragma unroll
    for (int j = 0; j < 4; ++j) {
        float m = dpp_max16(acc[4][j]);
        if (r == 15) pmx[wv * 16 + g * 4 + j] = m;
    }
    __syncthreads();
    if (tid < 112) {
        float s = pss[tid] + pss[112 + tid] + pss[224 + tid] + pss[336 + tid];
        float q = psq[tid] + psq[112 + tid] + psq[224 + tid] + psq[336 + tid];
        PS[(long)blk * 112 + tid] = s;
        PQ[(long)blk * 112 + tid] = q;
    } else if (tid < 128) {
        int kk = tid - 112;
        PM[(long)blk * 16 + kk] = fmaxf(fmaxf(pmx[kk], pmx[16 + kk]),
                                        fmaxf(pmx[32 + kk], pmx[48 + kk]));
    }
}

// ---------------- reduce partials: BN scale/shift + k rowmax ----------------
__global__ __launch_bounds__(256) void kred(const float* __restrict__ PS, const float* __restrict__ PQ,
                                            const float* __restrict__ PM,
                                            const float* gq, const float* bq,
                                            const float* gv, const float* bv, float* ws) {
    __shared__ float rs[256], rq[256];
    int bid = blockIdx.x, tid = threadIdx.x;
    if (bid < 96) {
        int c = bid;
        int oc = c < 64 ? c : c + 16;
        float s = 0.f, q = 0.f;
        for (int i = tid; i < 3456; i += 256) {
            s += PS[(long)i * 112 + oc];
            q += PQ[(long)i * 112 + oc];
        }
        rs[tid] = s; rq[tid] = q;
        __syncthreads();
        for (int st = 128; st > 0; st >>= 1) {
            if (tid < st) { rs[tid] += rs[tid + st]; rq[tid] += rq[tid + st]; }
            __syncthreads();
        }
        if (tid == 0) {
            const float inv_n = 1.f / 221184.f;
            float mean = rs[0] * inv_n;
            float var = rq[0] * inv_n - mean * mean;
            float g = c < 64 ? gq[c] : gv[c - 64];
            float bb = c < 64 ? bq[c] : bv[c - 64];
            float sc = g * rsqrtf(var + EPS);
            ws[O_SARR + c] = sc;
            ws[O_TARR + c] = bb - mean * sc;
        }
    } else {
        int row = bid - 96;
        int b = row >> 4, kk = row & 15;
        float m = -1e30f;
        for (int i = tid; i < 1728; i += 256) m = fmaxf(m, PM[((long)b * 1728 + i) * 16 + kk]);
        rs[tid] = m;
        __syncthreads();
        for (int st = 128; st > 0; st >>= 1) {
            if (tid < st) rs[tid] = fmaxf(rs[tid], rs[tid + st]);
            __syncthreads();
        }
        if (tid == 0) ws[O_RMAX + row] = rs[0];
    }
}

// ---------------- lam_c partials + softmax Z partials ----------------
__global__ __launch_bounds__(256) void klamcp(const float* __restrict__ kr, const unsigned int* __restrict__ vu,
                                              float* __restrict__ ws, float* __restrict__ lamcp) {
    __shared__ float es[16 * 512];
    const float* rmax = ws + O_RMAX;
    int bid = blockIdx.x;                  // 0..431
    int b = bid / 216, chunk = bid - b * 216;
    long p0 = (long)chunk * 512;
    int tid = threadIdx.x;
    for (int i = tid; i < 16 * 512; i += 256) {
        int rr = i >> 9, p = i & 511;
        es[i] = expf(kr[((long)b * 16 + rr) * NPOS + p0 + p] - rmax[b * 16 + rr]);
    }
    __syncthreads();
    int vp = tid >> 4, pl = tid & 15;
    const unsigned int* vpp = vu + ((long)b * 16 + vp) * NPOS + p0;
    float acc0[16], acc1[16];
#pragma unroll
    for (int k = 0; k < 16; ++k) { acc0[k] = 0.f; acc1[k] = 0.f; }
    for (int j = 0; j < 32; ++j) {
        int p = pl + 16 * j;
        unsigned int u = vpp[p];
        float v0 = bflo(u), v1 = bfhi(u);
#pragma unroll
        for (int k = 0; k < 16; ++k) {
            float e = es[k * 512 + p];
            acc0[k] = fmaf(e, v0, acc0[k]);
            acc1[k] = fmaf(e, v1, acc1[k]);
        }
    }
#pragma unroll
    for (int m = 1; m < 16; m <<= 1) {
#pragma unroll
        for (int k = 0; k < 16; ++k) {
            acc0[k] += __shfl_xor(acc0[k], m, 64);
            acc1[k] += __shfl_xor(acc1[k], m, 64);
        }
    }
    if (pl == 0) {
        long base = (long)bid * 512;
#pragma unroll
        for (int k = 0; k < 16; ++k) {
            lamcp[base + k * 32 + 2 * vp]     = acc0[k];
            lamcp[base + k * 32 + 2 * vp + 1] = acc1[k];
        }
    }
    {
        int rr = tid >> 4, j = tid & 15;
        float s = 0.f;
        const float* er = es + rr * 512 + j * 32;
#pragma unroll 8
        for (int i = 0; i < 32; ++i) s += er[i];
#pragma unroll
        for (int m = 1; m < 16; m <<= 1) s += __shfl_xor(s, m, 64);
        if (j == 0) ws[O_ZP + (long)bid * 16 + rr] = s;
    }
}

// ---------------- fold: RZI + SW/CW + lam_c reduce + q-BN fold (fused) ----------------
// 2 blocks (one per batch) x 512 threads
__global__ __launch_bounds__(512) void kfold(float* ws) {
    __shared__ float lamlds[512];
    int b = blockIdx.x, tid = threadIdx.x;
    const float* lamcp = ws + O_LAMCP;

    // per-thread lam_c partial sum over chunks (same order as before: c=0..215)
    float S = 0.f;
    for (int c = 0; c < 216; ++c) S += lamcp[((long)b * 216 + c) * 512 + tid];

    // softmax Z finalize (16 rows of this batch)
    if (tid < 16) {
        float z = 0.f;
        for (int c = 0; c < 216; ++c) z += ws[O_ZP + ((long)b * 216 + c) * 16 + tid];
        ws[O_RZI + b * 16 + tid] = 1.f / z;
    }
    // SW/CW (batch-independent): block 0 only
    if (b == 0) {
        for (int i = tid; i < 1728; i += 512) {
            int h = i / 432, r = i - h * 432, o = r >> 4, k = r & 15;
            ws[O_SW + i] = ws[O_SARR + h * 16 + k] * ws[O_WPT + o * 16 + k];
        }
        if (tid < 108) {
            int h = tid / 27, o = tid - h * 27;
            float s = 0.f;
            for (int k = 0; k < 16; ++k) s += ws[O_TARR + h * 16 + k] * ws[O_WPT + o * 16 + k];
            ws[O_CW + tid] = s;
        }
    }
    __syncthreads();

    // lam_c finalize (BN-v + 1/Z fold), kept in LDS
    {
        int kk = tid >> 5, v = tid & 31;
        float sv = ws[O_SARR + 64 + v], tv = ws[O_TARR + 64 + v];
        lamlds[tid] = sv * S * ws[O_RZI + b * 16 + kk] + tv;
    }
    __syncthreads();

    // LAMC2[b][h][k][v] = s_q[h*16+k] * lam_c[k*32+v]
    for (int r = tid; r < 2048; r += 512) {
        int h = r >> 9, k = (r >> 5) & 15;
        ws[O_LAMC2 + (long)b * 2048 + r] = ws[O_SARR + h * 16 + k] * lamlds[r & 511];
    }
    // BC[b][h][v] = sum_k t_q[h*16+k] * lam_c[k*32+v]
    if (tid < 128) {
        int h = tid >> 5, v = tid & 31;
        float s = 0.f;
#pragma unroll
        for (int k = 0; k < 16; ++k) s += ws[O_TARR + h * 16 + k] * lamlds[k * 32 + v];
        ws[O_BC + b * 128 + tid] = s;
    }
}

// ---------------- final fused kernel ----------------
// tile (d,h,w) = (2,4,16) = 128 pos, 512 threads (8 waves), halo z = 0..431
__global__ __launch_bounds__(512, 4) void kfinal(const unsigned int* __restrict__ qu,
                                                 const unsigned int* __restrict__ vu,
                                                 const float* __restrict__ ws, float* __restrict__ y) {
    __shared__ unsigned int vbnu[432 * 16];      // [z][8 slots x 16B], swz sl^=((z^(z>>2))&3)
    __shared__ unsigned short qwh[27 * 128 * 4]; // [o][pos][h] bf16
    __shared__ unsigned int qsu[128 * 32];       // [pos][8 slots x 16B], swz sl^=(pos&7)
    const float* sarr  = ws + O_SARR;
    const float* tarr  = ws + O_TARR;
    const float* swp   = ws + O_SW;
    const float* cwp   = ws + O_CW;
    const float* lamc2 = ws + O_LAMC2;
    const float* bcp   = ws + O_BC;

    int bid0 = blockIdx.x;                    // XCD-aware bijective swizzle (grid 1728 = 8*216)
    int bid = (bid0 & 7) * 216 + (bid0 >> 3);
    int b = bid / 864, t = bid - b * 864;     // tiles: d 24 x h 12 x w 3
    int td = t / 36, r = t - td * 36;
    int th = r / 3, tw = r - th * 3;
    int d0 = td * 2, h0 = th * 4, w0 = tw * 16;
    int tid = threadIdx.x;

    // phase A: halo load of packed v -> BN -> bf16 pair, swizzled [z][v]
    for (int i = tid; i < 16 * 432; i += 512) {
        int vp = i / 432, z = i - vp * 432;
        int zd = z / 108, rr = z - zd * 108;
        int zh = rr / 18, zw = rr - zh * 18;
        int gd = d0 - 1 + zd, gh = h0 - 1 + zh, gw = w0 - 1 + zw;
        unsigned int out = 0u;
        if ((unsigned)gd < 48u && (unsigned)gh < 48u && (unsigned)gw < 48u) {
            unsigned int u = vu[((long)b * 16 + vp) * NPOS + gd * 2304 + gh * 48 + gw];
            float a = fmaf(bflo(u), sarr[64 + 2 * vp], tarr[64 + 2 * vp]);
            float c = fmaf(bfhi(u), sarr[65 + 2 * vp], tarr[65 + 2 * vp]);
            out = cvtpk(a, c);
        }
        int sl = (vp >> 2) ^ ((z ^ (z >> 2)) & 3);
        vbnu[z * 16 + sl * 4 + (vp & 3)] = out;
    }

    // phase B: qw + q stash
    int lane = tid & 63;
    int wv = __builtin_amdgcn_readfirstlane(tid >> 6);
    int hsel = wv & 3, psel = wv >> 2;
    int pos_l = psel * 64 + lane;
    int lh = lane >> 4, lw = lane & 15;
    int goff = (d0 + psel) * 2304 + (h0 + lh) * 48 + (w0 + lw);
    {
        unsigned int uq[8];
        float qk[16];
        const unsigned int* qb = qu + ((long)b * 32 + hsel * 8) * NPOS + goff;
#pragma unroll
        for (int m = 0; m < 8; ++m) {
            uq[m] = qb[(long)m * NPOS];
            qk[2 * m] = bflo(uq[m]);
            qk[2 * m + 1] = bfhi(uq[m]);
        }
#pragma unroll
        for (int o = 0; o < 27; ++o) {
            float a = cwp[hsel * 27 + o];
            const float* swrow = swp + (hsel * 27 + o) * 16;
#pragma unroll
            for (int k = 0; k < 16; ++k) a = fmaf(qk[k], swrow[k], a);
            qwh[(o * 128 + pos_l) * 4 + hsel] = (unsigned short)cvtpk(a, a);
        }
        uint4 w0v = make_uint4(uq[0], uq[1], uq[2], uq[3]);
        uint4 w1v = make_uint4(uq[4], uq[5], uq[6], uq[7]);
        *(uint4*)(qsu + pos_l * 32 + (((2 * hsel) ^ (pos_l & 7)) << 2)) = w0v;
        *(uint4*)(qsu + pos_l * 32 + (((2 * hsel + 1) ^ (pos_l & 7)) << 2)) = w1v;
    }
    __syncthreads();

    // phase C: (pos_l, v-group vg -> v0..v0+7), all 4 h
    int vg = wv & 3;
    int v0 = vg * 8;
    f32x2 acc2[4][4];
#pragma unroll
    for (int hh = 0; hh < 4; ++hh)
#pragma unroll
        for (int p = 0; p < 4; ++p) {
            acc2[hh][p][0] = bcp[(b * 4 + hh) * 32 + v0 + 2 * p];
            acc2[hh][p][1] = bcp[(b * 4 + hh) * 32 + v0 + 2 * p + 1];
        }

    // y_c: q (bf16 from LDS) x s_q-folded lam_c (scalar fmaf — compiler schedules best)
#pragma unroll
    for (int s = 0; s < 8; ++s) {
        uint4 uq = *(const uint4*)(qsu + pos_l * 32 + ((s ^ (pos_l & 7)) << 2));
        int hh = s >> 1, k0 = (s & 1) * 8;
        float qa[8];
        qa[0] = bflo(uq.x); qa[1] = bfhi(uq.x);
        qa[2] = bflo(uq.y); qa[3] = bfhi(uq.y);
        qa[4] = bflo(uq.z); qa[5] = bfhi(uq.z);
        qa[6] = bflo(uq.w); qa[7] = bfhi(uq.w);
#pragma unroll
        for (int j = 0; j < 8; ++j) {
            const float* l2 = lamc2 + (((b * 4 + hh) * 16 + k0 + j) << 5) + v0;
#pragma unroll
            for (int p = 0; p < 4; ++p) {
                acc2[hh][p][0] = fmaf(qa[j], l2[2 * p], acc2[hh][p][0]);
                acc2[hh][p][1] = fmaf(qa[j], l2[2 * p + 1], acc2[hh][p][1]);
            }
        }
    }

    // y_p: 27-point stencil with packed-fp32 FMA
    int zb = psel * 108 + lh * 18 + lw;
#pragma unroll
    for (int od = 0; od < 3; ++od)
#pragma unroll
    for (int oh = 0; oh < 3; ++oh)
#pragma unroll
    for (int ow = 0; ow < 3; ++ow) {
        int o = od * 9 + oh * 3 + ow;
        int z = zb + od * 108 + oh * 18 + ow;
        int sl = vg ^ ((z ^ (z >> 2)) & 3);
        uint4 u = *(const uint4*)(vbnu + z * 16 + (sl << 2));
        uint2 uqw = *(const uint2*)(qwh + ((o * 128 + pos_l) << 2));
        f32x2 s0; s0[0] = bflo(u.x); s0[1] = bfhi(u.x);
        f32x2 s1; s1[0] = bflo(u.y); s1[1] = bfhi(u.y);
        f32x2 s2; s2[0] = bflo(u.z); s2[1] = bfhi(u.z);
        f32x2 s3; s3[0] = bflo(u.w); s3[1] = bfhi(u.w);
        float q0 = bflo(uqw.x), q1 = bfhi(uqw.x);
        float q2 = bflo(uqw.y), q3 = bfhi(uqw.y);
        f32x2 qd0; qd0[0] = q0; qd0[1] = q0;
        f32x2 qd1; qd1[0] = q1; qd1[1] = q1;
        f32x2 qd2; qd2[0] = q2; qd2[1] = q2;
        f32x2 qd3; qd3[0] = q3; qd3[1] = q3;
        pkfma(acc2[0][0], qd0, s0); pkfma(acc2[0][1], qd0, s1);
        pkfma(acc2[0][2], qd0, s2); pkfma(acc2[0][3], qd0, s3);
        pkfma(acc2[1][0], qd1, s0); pkfma(acc2[1][1], qd1, s1);
        pkfma(acc2[1][2], qd1, s2); pkfma(acc2[1][3], qd1, s3);
        pkfma(acc2[2][0], qd2, s0); pkfma(acc2[2][1], qd2, s1);
        pkfma(acc2[2][2], qd2, s2); pkfma(acc2[2][3], qd2, s3);
        pkfma(acc2[3][0], qd3, s0); pkfma(acc2[3][1], qd3, s1);
        pkfma(acc2[3][2], qd3, s2); pkfma(acc2[3][3], qd3, s3);
    }

    long pbase = (long)b * 128 * NPOS + goff;
#pragma unroll
    for (int hh = 0; hh < 4; ++hh)
#pragma unroll
        for (int p = 0; p < 4; ++p) {
            y[pbase + (long)(hh * 32 + v0 + 2 * p) * NPOS]     = acc2[hh][p][0];
            y[pbase + (long)(hh * 32 + v0 + 2 * p + 1) * NPOS] = acc2[hh][p][1];
        }
}

extern "C" void kernel_launch(void* const* d_in, const int* in_sizes, int n_in,
                              void* d_out, int out_size, void* d_ws, size_t ws_size,
                              hipStream_t stream) {
    const float* x    = (const float*)d_in[0];
    const float* Wq   = (const float*)d_in[1];
    const float* Wk   = (const float*)d_in[2];
    const float* Wv   = (const float*)d_in[3];
    const float* Wpos = (const float*)d_in[4];
    const float* gq   = (const float*)d_in[5];
    const float* bq   = (const float*)d_in[6];
    const float* gv   = (const float*)d_in[7];
    const float* bv   = (const float*)d_in[8];
    float* ws = (float*)d_ws;
    float* y  = (float*)d_out;
    unsigned int* qu = (unsigned int*)(ws + O_Q);
    float*        kr = ws + O_K;
    unsigned int* vu = (unsigned int*)(ws + O_V);
    // partial-sum scratch inside d_out (fully overwritten by kfinal afterwards)
    float* PS = y;                 // [3456][112]
    float* PQ = y + 387072;        // [3456][112]
    float* PM = y + 774144;        // [3456][16]

    ksetup <<<30,   256, 0, stream>>>(Wq, Wk, Wv, Wpos, ws);
    kproj  <<<3456, 256, 0, stream>>>(x, ws, qu, kr, vu, PS, PQ, PM);
    kred   <<<128,  256, 0, stream>>>(PS, PQ, PM, gq, bq, gv, bv, ws);
    klamcp <<<432,  256, 0, stream>>>(kr, vu, ws, ws + O_LAMCP);
    kfold  <<<2,    512, 0, stream>>>(ws);
    kfinal <<<1728, 512, 0, stream>>>(qu, vu, ws, y);
}

// Round 18
// 211.712 us; speedup vs baseline: 1.0061x; 1.0061x over previous
//
#include <hip/hip_runtime.h>
#include <math.h>

#define NPOS 110592   // 48*48*48
#define EPS 1e-5f

using bf16x8 = __attribute__((ext_vector_type(8))) short;
using f32x4  = __attribute__((ext_vector_type(4))) float;
using f32x2  = __attribute__((ext_vector_type(2))) float;

// ws layout (float-slot offsets)
constexpr long O_WB    = 0;        // 112x128 bf16 = 7168 slots (W[oc][c])
constexpr long O_WPT   = 7168;     // 27*16 fp32 (wposT[o][k])
constexpr long O_SARR  = 7600;     // 96  (BN scale: 0..63 q, 64..95 v)
constexpr long O_TARR  = 7696;     // 96  (BN shift)
constexpr long O_RMAX  = 7792;     // 32  (softmax rowmax per (b,k))
constexpr long O_ZP    = 7824;     // 432*16 softmax denom partials
constexpr long O_RZI   = 14736;    // 32 (1/Z)
constexpr long O_SW    = 14768;    // 4*27*16 (s_q-folded conv weights)
constexpr long O_CW    = 16496;    // 108(+pad) (t_q-folded conv bias)
constexpr long O_LAMC  = 16608;    // 2*16*32 (unused scratch now)
constexpr long O_LAMC2 = 17632;    // 2*4*16*32 (s_q-folded lam_c)
constexpr long O_BC    = 21728;    // 2*4*32 (t_q-folded lam_c bias)
constexpr long O_LAMCP = 21984;    // 2*216*512 lam_c partials
constexpr long O_Q     = 243168;   // u32[2][32][NPOS] bf16-pairs
constexpr long O_K     = 7321056;  // f32[2][16][NPOS]
constexpr long O_V     = 10860000; // u32[2][16][NPOS] bf16-pairs
// total ~57.6 MB

__device__ inline unsigned short f2bf(float f) {
    unsigned int u = __float_as_uint(f);
    u += 0x7FFFu + ((u >> 16) & 1u);   // RNE
    return (unsigned short)(u >> 16);
}
__device__ inline float bflo(unsigned int u) { return __uint_as_float(u << 16); }
__device__ inline float bfhi(unsigned int u) { return __uint_as_float(u & 0xFFFF0000u); }
__device__ inline unsigned int cvtpk(float a, float b) {
    unsigned int r;
    asm("v_cvt_pk_bf16_f32 %0, %1, %2" : "=v"(r) : "v"(a), "v"(b));
    return r;
}
__device__ inline void pkfma(f32x2& c, f32x2 a, f32x2 b) {
    asm("v_pk_fma_f32 %0, %1, %2, %0" : "+v"(c) : "v"(a), "v"(b));
}

// DPP row reductions (VALU pipe, no LDS): lane 15 of each 16-lane row gets the result.
template<int CTRL>
__device__ inline float dpp_shr(float x) {
    int xi = __builtin_bit_cast(int, x);
    return __builtin_bit_cast(float, __builtin_amdgcn_update_dpp(xi, xi, CTRL, 0xf, 0xf, false));
}
__device__ inline float dpp_sum16(float x) {
    x += dpp_shr<0x111>(x);
    x += dpp_shr<0x112>(x);
    x += dpp_shr<0x114>(x);
    x += dpp_shr<0x118>(x);
    return x;
}
__device__ inline float dpp_max16(float x) {
    x = fmaxf(x, dpp_shr<0x111>(x));
    x = fmaxf(x, dpp_shr<0x112>(x));
    x = fmaxf(x, dpp_shr<0x114>(x));
    x = fmaxf(x, dpp_shr<0x118>(x));
    return x;
}

// ---------------- setup: bf16 weights [oc][c] + wposT ----------------
__global__ __launch_bounds__(256) void ksetup(const float* Wq, const float* Wk, const float* Wv,
                                              const float* Wpos, float* ws) {
    int i = blockIdx.x * 256 + threadIdx.x;
    if (i < 7168) {
        int oc = i >> 6, cp = i & 63;
        int c = 2 * cp;
        float v0, v1;
        if (oc < 64)      { v0 = Wq[oc * 128 + c];        v1 = Wq[oc * 128 + c + 1]; }
        else if (oc < 80) { v0 = Wk[(oc - 64) * 128 + c]; v1 = Wk[(oc - 64) * 128 + c + 1]; }
        else              { v0 = Wv[(oc - 80) * 128 + c]; v1 = Wv[(oc - 80) * 128 + c + 1]; }
        ((unsigned int*)(ws + O_WB))[i] = (unsigned int)f2bf(v0) | ((unsigned int)f2bf(v1) << 16);
    } else if (i < 7600) {
        int j = i - 7168;
        int o = j >> 4, k = j & 15;
        ws[O_WPT + j] = Wpos[k * 27 + o];   // o = od*9+oh*3+ow
    }
}

// ---------------- projection via MFMA + fused stat partials (DPP reduce) ----------------
__global__ __launch_bounds__(256, 4) void kproj(const float* __restrict__ x, const float* __restrict__ ws,
                                                unsigned int* __restrict__ qu, float* __restrict__ kr,
                                                unsigned int* __restrict__ vu,
                                                float* __restrict__ PS, float* __restrict__ PQ,
                                                float* __restrict__ PM) {
    __shared__ unsigned int xsu[64 * 68];   // [pos][c-pair] bf16, row = 272 B (16B aligned)
    __shared__ float pss[4 * 112], psq[4 * 112], pmx[4 * 16];
    const unsigned short* WBu = (const unsigned short*)(ws + O_WB);

    int blk0 = blockIdx.x;                // XCD-aware bijective swizzle (grid 3456 = 8*432)
    int blk = (blk0 & 7) * 432 + (blk0 >> 3);
    int b = blk / 1728, tile = blk - b * 1728;
    long base = (long)b * 128 * NPOS + (long)tile * 64;
    int tid = threadIdx.x;

    // stage x tile transposed to [pos][c] bf16; b128 writes (4 iters)
    for (int i = tid; i < 1024; i += 256) {
        int cc = i >> 6, p = i & 63;      // cc: group of 8 channels
        const float* xp = x + base + (long)(8 * cc) * NPOS + p;
        uint4 w;
        w.x = cvtpk(xp[0],               xp[(long)NPOS]);
        w.y = cvtpk(xp[2 * (long)NPOS],  xp[3 * (long)NPOS]);
        w.z = cvtpk(xp[4 * (long)NPOS],  xp[5 * (long)NPOS]);
        w.w = cvtpk(xp[6 * (long)NPOS],  xp[7 * (long)NPOS]);
        *(uint4*)(xsu + p * 68 + cc * 4) = w;
    }
    __syncthreads();

    int lane = tid & 63;
    int wv = __builtin_amdgcn_readfirstlane(tid >> 6);
    int r = lane & 15, g = lane >> 4;

    f32x4 acc[7];
#pragma unroll
    for (int t = 0; t < 7; ++t) acc[t] = (f32x4){0.f, 0.f, 0.f, 0.f};

    const unsigned short* xrow = (const unsigned short*)xsu + (wv * 16 + r) * 136;
#pragma unroll
    for (int ks = 0; ks < 4; ++ks) {
        bf16x8 bfrag = *(const bf16x8*)(const void*)(xrow + ks * 32 + g * 8);
#pragma unroll
        for (int t = 0; t < 7; ++t) {
            bf16x8 afrag = *(const bf16x8*)(const void*)(WBu + (t * 16 + r) * 128 + ks * 32 + g * 8);
            acc[t] = __builtin_amdgcn_mfma_f32_16x16x32_bf16(afrag, bfrag, acc[t], 0, 0, 0);
        }
    }

    long pos = (long)tile * 64 + wv * 16 + r;
    // q (t 0..3): bf16-pair u32
#pragma unroll
    for (int t = 0; t < 4; ++t)
#pragma unroll
        for (int jp = 0; jp < 2; ++jp)
            qu[((long)b * 32 + t * 8 + g * 2 + jp) * NPOS + pos] = cvtpk(acc[t][2 * jp], acc[t][2 * jp + 1]);
    // k (t=4): fp32
#pragma unroll
    for (int j = 0; j < 4; ++j)
        kr[((long)b * 16 + g * 4 + j) * NPOS + pos] = acc[4][j];
    // v (t 5..6): bf16-pair u32
#pragma unroll
    for (int t = 5; t < 7; ++t)
#pragma unroll
        for (int jp = 0; jp < 2; ++jp)
            vu[((long)b * 16 + (t - 5) * 8 + g * 2 + jp) * NPOS + pos] = cvtpk(acc[t][2 * jp], acc[t][2 * jp + 1]);

    // fused stat partials via DPP (VALU pipe); row result lands in lane r==15
#pragma unroll
    for (int t = 0; t < 7; ++t) {
#pragma unroll
        for (int j = 0; j < 4; ++j) {
            float v = acc[t][j];
            float s = dpp_sum16(v);
            float q = dpp_sum16(v * v);
            if (r == 15) {
                int oc = t * 16 + g * 4 + j;
                pss[wv * 112 + oc] = s;
                psq[wv * 112 + oc] = q;
            }
        }
    }
#pragma unroll
    for (int j = 0; j < 4; ++j) {
        float m = dpp_max16(acc[4][j]);
        if (r == 15) pmx[wv * 16 + g * 4 + j] = m;
    }
    __syncthreads();
    if (tid < 112) {
        float s = pss[tid] + pss[112 + tid] + pss[224 + tid] + pss[336 + tid];
        float q = psq[tid] + psq[112 + tid] + psq[224 + tid] + psq[336 + tid];
        PS[(long)blk * 112 + tid] = s;
        PQ[(long)blk * 112 + tid] = q;
    } else if (tid < 128) {
        int kk = tid - 112;
        PM[(long)blk * 16 + kk] = fmaxf(fmaxf(pmx[kk], pmx[16 + kk]),
                                        fmaxf(pmx[32 + kk], pmx[48 + kk]));
    }
}

// ---------------- reduce partials: BN scale/shift + k rowmax ----------------
__global__ __launch_bounds__(256) void kred(const float* __restrict__ PS, const float* __restrict__ PQ,
                                            const float* __restrict__ PM,
                                            const float* gq, const float* bq,
                                            const float* gv, const float* bv, float* ws) {
    __shared__ float rs[256], rq[256];
    int bid = blockIdx.x, tid = threadIdx.x;
    if (bid < 96) {
        int c = bid;
        int oc = c < 64 ? c : c + 16;
        float s = 0.f, q = 0.f;
        for (int i = tid; i < 3456; i += 256) {
            s += PS[(long)i * 112 + oc];
            q += PQ[(long)i * 112 + oc];
        }
        rs[tid] = s; rq[tid] = q;
        __syncthreads();
        for (int st = 128; st > 0; st >>= 1) {
            if (tid < st) { rs[tid] += rs[tid + st]; rq[tid] += rq[tid + st]; }
            __syncthreads();
        }
        if (tid == 0) {
            const float inv_n = 1.f / 221184.f;
            float mean = rs[0] * inv_n;
            float var = rq[0] * inv_n - mean * mean;
            float g = c < 64 ? gq[c] : gv[c - 64];
            float bb = c < 64 ? bq[c] : bv[c - 64];
            float sc = g * rsqrtf(var + EPS);
            ws[O_SARR + c] = sc;
            ws[O_TARR + c] = bb - mean * sc;
        }
    } else {
        int row = bid - 96;
        int b = row >> 4, kk = row & 15;
        float m = -1e30f;
        for (int i = tid; i < 1728; i += 256) m = fmaxf(m, PM[((long)b * 1728 + i) * 16 + kk]);
        rs[tid] = m;
        __syncthreads();
        for (int st = 128; st > 0; st >>= 1) {
            if (tid < st) rs[tid] = fmaxf(rs[tid], rs[tid + st]);
            __syncthreads();
        }
        if (tid == 0) ws[O_RMAX + row] = rs[0];
    }
}

// ---------------- lam_c partials + softmax Z partials ----------------
__global__ __launch_bounds__(256) void klamcp(const float* __restrict__ kr, const unsigned int* __restrict__ vu,
                                              float* __restrict__ ws, float* __restrict__ lamcp) {
    __shared__ float es[16 * 512];
    const float* rmax = ws + O_RMAX;
    int bid = blockIdx.x;                  // 0..431
    int b = bid / 216, chunk = bid - b * 216;
    long p0 = (long)chunk * 512;
    int tid = threadIdx.x;
    for (int i = tid; i < 16 * 512; i += 256) {
        int rr = i >> 9, p = i & 511;
        es[i] = expf(kr[((long)b * 16 + rr) * NPOS + p0 + p] - rmax[b * 16 + rr]);
    }
    __syncthreads();
    int vp = tid >> 4, pl = tid & 15;
    const unsigned int* vpp = vu + ((long)b * 16 + vp) * NPOS + p0;
    float acc0[16], acc1[16];
#pragma unroll
    for (int k = 0; k < 16; ++k) { acc0[k] = 0.f; acc1[k] = 0.f; }
    for (int j = 0; j < 32; ++j) {
        int p = pl + 16 * j;
        unsigned int u = vpp[p];
        float v0 = bflo(u), v1 = bfhi(u);
#pragma unroll
        for (int k = 0; k < 16; ++k) {
            float e = es[k * 512 + p];
            acc0[k] = fmaf(e, v0, acc0[k]);
            acc1[k] = fmaf(e, v1, acc1[k]);
        }
    }
#pragma unroll
    for (int m = 1; m < 16; m <<= 1) {
#pragma unroll
        for (int k = 0; k < 16; ++k) {
            acc0[k] += __shfl_xor(acc0[k], m, 64);
            acc1[k] += __shfl_xor(acc1[k], m, 64);
        }
    }
    if (pl == 0) {
        long base = (long)bid * 512;
#pragma unroll
        for (int k = 0; k < 16; ++k) {
            lamcp[base + k * 32 + 2 * vp]     = acc0[k];
            lamcp[base + k * 32 + 2 * vp + 1] = acc1[k];
        }
    }
    {
        int rr = tid >> 4, j = tid & 15;
        float s = 0.f;
        const float* er = es + rr * 512 + j * 32;
#pragma unroll 8
        for (int i = 0; i < 32; ++i) s += er[i];
#pragma unroll
        for (int m = 1; m < 16; m <<= 1) s += __shfl_xor(s, m, 64);
        if (j == 0) ws[O_ZP + (long)bid * 16 + rr] = s;
    }
}

// ---------------- fold: RZI + SW/CW + lam_c reduce + q-BN fold (fused) ----------------
// 2 blocks (one per batch) x 512 threads
__global__ __launch_bounds__(512) void kfold(float* ws) {
    __shared__ float lamlds[512];
    int b = blockIdx.x, tid = threadIdx.x;
    const float* lamcp = ws + O_LAMCP;

    // per-thread lam_c partial sum over chunks (same order as before: c=0..215)
    float S = 0.f;
    for (int c = 0; c < 216; ++c) S += lamcp[((long)b * 216 + c) * 512 + tid];

    // softmax Z finalize (16 rows of this batch)
    if (tid < 16) {
        float z = 0.f;
        for (int c = 0; c < 216; ++c) z += ws[O_ZP + ((long)b * 216 + c) * 16 + tid];
        ws[O_RZI + b * 16 + tid] = 1.f / z;
    }
    // SW/CW (batch-independent): block 0 only
    if (b == 0) {
        for (int i = tid; i < 1728; i += 512) {
            int h = i / 432, r = i - h * 432, o = r >> 4, k = r & 15;
            ws[O_SW + i] = ws[O_SARR + h * 16 + k] * ws[O_WPT + o * 16 + k];
        }
        if (tid < 108) {
            int h = tid / 27, o = tid - h * 27;
            float s = 0.f;
            for (int k = 0; k < 16; ++k) s += ws[O_TARR + h * 16 + k] * ws[O_WPT + o * 16 + k];
            ws[O_CW + tid] = s;
        }
    }
    __syncthreads();

    // lam_c finalize (BN-v + 1/Z fold), kept in LDS
    {
        int kk = tid >> 5, v = tid & 31;
        float sv = ws[O_SARR + 64 + v], tv = ws[O_TARR + 64 + v];
        lamlds[tid] = sv * S * ws[O_RZI + b * 16 + kk] + tv;
    }
    __syncthreads();

    // LAMC2[b][h][k][v] = s_q[h*16+k] * lam_c[k*32+v]
    for (int r = tid; r < 2048; r += 512) {
        int h = r >> 9, k = (r >> 5) & 15;
        ws[O_LAMC2 + (long)b * 2048 + r] = ws[O_SARR + h * 16 + k] * lamlds[r & 511];
    }
    // BC[b][h][v] = sum_k t_q[h*16+k] * lam_c[k*32+v]
    if (tid < 128) {
        int h = tid >> 5, v = tid & 31;
        float s = 0.f;
#pragma unroll
        for (int k = 0; k < 16; ++k) s += ws[O_TARR + h * 16 + k] * lamlds[k * 32 + v];
        ws[O_BC + b * 128 + tid] = s;
    }
}

// ---------------- final fused kernel ----------------
// tile (d,h,w) = (2,4,16) = 128 pos, 512 threads (8 waves), halo z = 0..431
__global__ __launch_bounds__(512, 4) void kfinal(const unsigned int* __restrict__ qu,
                                                 const unsigned int* __restrict__ vu,
                                                 const float* __restrict__ ws, float* __restrict__ y) {
    __shared__ unsigned int vbnu[432 * 16];      // [z][8 slots x 16B], swz sl^=((z^(z>>2))&3)
    __shared__ unsigned short qwh[27 * 128 * 4]; // [o][pos][h] bf16
    __shared__ unsigned int qsu[128 * 32];       // [pos][8 slots x 16B], swz sl^=(pos&7)
    const float* sarr  = ws + O_SARR;
    const float* tarr  = ws + O_TARR;
    const float* swp   = ws + O_SW;
    const float* cwp   = ws + O_CW;
    const float* lamc2 = ws + O_LAMC2;
    const float* bcp   = ws + O_BC;

    int bid0 = blockIdx.x;                    // XCD-aware bijective swizzle (grid 1728 = 8*216)
    int bid = (bid0 & 7) * 216 + (bid0 >> 3);
    int b = bid / 864, t = bid - b * 864;     // tiles: d 24 x h 12 x w 3
    int td = t / 36, r = t - td * 36;
    int th = r / 3, tw = r - th * 3;
    int d0 = td * 2, h0 = th * 4, w0 = tw * 16;
    int tid = threadIdx.x;

    // phase A: halo load of packed v -> BN -> bf16 pair, swizzled [z][v]
    for (int i = tid; i < 16 * 432; i += 512) {
        int vp = i / 432, z = i - vp * 432;
        int zd = z / 108, rr = z - zd * 108;
        int zh = rr / 18, zw = rr - zh * 18;
        int gd = d0 - 1 + zd, gh = h0 - 1 + zh, gw = w0 - 1 + zw;
        unsigned int out = 0u;
        if ((unsigned)gd < 48u && (unsigned)gh < 48u && (unsigned)gw < 48u) {
            unsigned int u = vu[((long)b * 16 + vp) * NPOS + gd * 2304 + gh * 48 + gw];
            float a = fmaf(bflo(u), sarr[64 + 2 * vp], tarr[64 + 2 * vp]);
            float c = fmaf(bfhi(u), sarr[65 + 2 * vp], tarr[65 + 2 * vp]);
            out = cvtpk(a, c);
        }
        int sl = (vp >> 2) ^ ((z ^ (z >> 2)) & 3);
        vbnu[z * 16 + sl * 4 + (vp & 3)] = out;
    }

    // phase B: qw + q stash
    int lane = tid & 63;
    int wv = __builtin_amdgcn_readfirstlane(tid >> 6);
    int hsel = wv & 3, psel = wv >> 2;
    int pos_l = psel * 64 + lane;
    int lh = lane >> 4, lw = lane & 15;
    int goff = (d0 + psel) * 2304 + (h0 + lh) * 48 + (w0 + lw);
    {
        unsigned int uq[8];
        float qk[16];
        const unsigned int* qb = qu + ((long)b * 32 + hsel * 8) * NPOS + goff;
#pragma unroll
        for (int m = 0; m < 8; ++m) {
            uq[m] = qb[(long)m * NPOS];
            qk[2 * m] = bflo(uq[m]);
            qk[2 * m + 1] = bfhi(uq[m]);
        }
#pragma unroll
        for (int o = 0; o < 27; ++o) {
            float a = cwp[hsel * 27 + o];
            const float* swrow = swp + (hsel * 27 + o) * 16;
#pragma unroll
            for (int k = 0; k < 16; ++k) a = fmaf(qk[k], swrow[k], a);
            qwh[(o * 128 + pos_l) * 4 + hsel] = (unsigned short)cvtpk(a, a);
        }
        uint4 w0v = make_uint4(uq[0], uq[1], uq[2], uq[3]);
        uint4 w1v = make_uint4(uq[4], uq[5], uq[6], uq[7]);
        *(uint4*)(qsu + pos_l * 32 + (((2 * hsel) ^ (pos_l & 7)) << 2)) = w0v;
        *(uint4*)(qsu + pos_l * 32 + (((2 * hsel + 1) ^ (pos_l & 7)) << 2)) = w1v;
    }
    __syncthreads();

    // phase C: (pos_l, v-group vg -> v0..v0+7), all 4 h
    int vg = wv & 3;
    int v0 = vg * 8;
    f32x2 acc2[4][4];
#pragma unroll
    for (int hh = 0; hh < 4; ++hh)
#pragma unroll
        for (int p = 0; p < 4; ++p) {
            acc2[hh][p][0] = bcp[(b * 4 + hh) * 32 + v0 + 2 * p];
            acc2[hh][p][1] = bcp[(b * 4 + hh) * 32 + v0 + 2 * p + 1];
        }

    // y_c: q (bf16 from LDS) x s_q-folded lam_c (scalar fmaf — compiler schedules best)
#pragma unroll
    for (int s = 0; s < 8; ++s) {
        uint4 uq = *(const uint4*)(qsu + pos_l * 32 + ((s ^ (pos_l & 7)) << 2));
        int hh = s >> 1, k0 = (s & 1) * 8;
        float qa[8];
        qa[0] = bflo(uq.x); qa[1] = bfhi(uq.x);
        qa[2] = bflo(uq.y); qa[3] = bfhi(uq.y);
        qa[4] = bflo(uq.z); qa[5] = bfhi(uq.z);
        qa[6] = bflo(uq.w); qa[7] = bfhi(uq.w);
#pragma unroll
        for (int j = 0; j < 8; ++j) {
            const float* l2 = lamc2 + (((b * 4 + hh) * 16 + k0 + j) << 5) + v0;
#pragma unroll
            for (int p = 0; p < 4; ++p) {
                acc2[hh][p][0] = fmaf(qa[j], l2[2 * p], acc2[hh][p][0]);
                acc2[hh][p][1] = fmaf(qa[j], l2[2 * p + 1], acc2[hh][p][1]);
            }
        }
    }

    // y_p: 27-point stencil with packed-fp32 FMA
    int zb = psel * 108 + lh * 18 + lw;
#pragma unroll
    for (int od = 0; od < 3; ++od)
#pragma unroll
    for (int oh = 0; oh < 3; ++oh)
#pragma unroll
    for (int ow = 0; ow < 3; ++ow) {
        int o = od * 9 + oh * 3 + ow;
        int z = zb + od * 108 + oh * 18 + ow;
        int sl = vg ^ ((z ^ (z >> 2)) & 3);
        uint4 u = *(const uint4*)(vbnu + z * 16 + (sl << 2));
        uint2 uqw = *(const uint2*)(qwh + ((o * 128 + pos_l) << 2));
        f32x2 s0; s0[0] = bflo(u.x); s0[1] = bfhi(u.x);
        f32x2 s1; s1[0] = bflo(u.y); s1[1] = bfhi(u.y);
        f32x2 s2; s2[0] = bflo(u.z); s2[1] = bfhi(u.z);
        f32x2 s3; s3[0] = bflo(u.w); s3[1] = bfhi(u.w);
        float q0 = bflo(uqw.x), q1 = bfhi(uqw.x);
        float q2 = bflo(uqw.y), q3 = bfhi(uqw.y);
        f32x2 qd0; qd0[0] = q0; qd0[1] = q0;
        f32x2 qd1; qd1[0] = q1; qd1[1] = q1;
        f32x2 qd2; qd2[0] = q2; qd2[1] = q2;
        f32x2 qd3; qd3[0] = q3; qd3[1] = q3;
        pkfma(acc2[0][0], qd0, s0); pkfma(acc2[0][1], qd0, s1);
        pkfma(acc2[0][2], qd0, s2); pkfma(acc2[0][3], qd0, s3);
        pkfma(acc2[1][0], qd1, s0); pkfma(acc2[1][1], qd1, s1);
        pkfma(acc2[1][2], qd1, s2); pkfma(acc2[1][3], qd1, s3);
        pkfma(acc2[2][0], qd2, s0); pkfma(acc2[2][1], qd2, s1);
        pkfma(acc2[2][2], qd2, s2); pkfma(acc2[2][3], qd2, s3);
        pkfma(acc2[3][0], qd3, s0); pkfma(acc2[3][1], qd3, s1);
        pkfma(acc2[3][2], qd3, s2); pkfma(acc2[3][3], qd3, s3);
    }

    long pbase = (long)b * 128 * NPOS + goff;
#pragma unroll
    for (int hh = 0; hh < 4; ++hh)
#pragma unroll
        for (int p = 0; p < 4; ++p) {
            y[pbase + (long)(hh * 32 + v0 + 2 * p) * NPOS]     = acc2[hh][p][0];
            y[pbase + (long)(hh * 32 + v0 + 2 * p + 1) * NPOS] = acc2[hh][p][1];
        }
}

extern "C" void kernel_launch(void* const* d_in, const int* in_sizes, int n_in,
                              void* d_out, int out_size, void* d_ws, size_t ws_size,
                              hipStream_t stream) {
    const float* x    = (const float*)d_in[0];
    const float* Wq   = (const float*)d_in[1];
    const float* Wk   = (const float*)d_in[2];
    const float* Wv   = (const float*)d_in[3];
    const float* Wpos = (const float*)d_in[4];
    const float* gq   = (const float*)d_in[5];
    const float* bq   = (const float*)d_in[6];
    const float* gv   = (const float*)d_in[7];
    const float* bv   = (const float*)d_in[8];
    float* ws = (float*)d_ws;
    float* y  = (float*)d_out;
    unsigned int* qu = (unsigned int*)(ws + O_Q);
    float*        kr = ws + O_K;
    unsigned int* vu = (unsigned int*)(ws + O_V);
    // partial-sum scratch inside d_out (fully overwritten by kfinal afterwards)
    float* PS = y;                 // [3456][112]
    float* PQ = y + 387072;        // [3456][112]
    float* PM = y + 774144;        // [3456][16]

    ksetup <<<30,   256, 0, stream>>>(Wq, Wk, Wv, Wpos, ws);
    kproj  <<<3456, 256, 0, stream>>>(x, ws, qu, kr, vu, PS, PQ, PM);
    kred   <<<128,  256, 0, stream>>>(PS, PQ, PM, gq, bq, gv, bv, ws);
    klamcp <<<432,  256, 0, stream>>>(kr, vu, ws, ws + O_LAMCP);
    kfold  <<<2,    512, 0, stream>>>(ws);
    kfinal <<<1728, 512, 0, stream>>>(qu, vu, ws, y);
}

// Round 19
// 210.795 us; speedup vs baseline: 1.0105x; 1.0044x over previous
//
#include <hip/hip_runtime.h>
#include <math.h>

#define NPOS 110592   // 48*48*48
#define EPS 1e-5f

using bf16x8 = __attribute__((ext_vector_type(8))) short;
using f32x4  = __attribute__((ext_vector_type(4))) float;
using f32x2  = __attribute__((ext_vector_type(2))) float;

// ws layout (float-slot offsets)
constexpr long O_WB    = 0;        // 112x128 bf16 = 7168 slots (W[oc][c])
constexpr long O_WPT   = 7168;     // 27*16 fp32 (wposT[o][k])
constexpr long O_SARR  = 7600;     // 96  (BN scale: 0..63 q, 64..95 v)
constexpr long O_TARR  = 7696;     // 96  (BN shift)
constexpr long O_RMAX  = 7792;     // 32  (softmax rowmax per (b,k))
constexpr long O_ZP    = 7824;     // 432*16 softmax denom partials
constexpr long O_RZI   = 14736;    // 32 (1/Z)
constexpr long O_SW    = 14768;    // 4*27*16 (s_q-folded conv weights)
constexpr long O_CW    = 16496;    // 108(+pad) (t_q-folded conv bias)
constexpr long O_LAMC  = 16608;    // 2*16*32 (unused scratch now)
constexpr long O_LAMC2 = 17632;    // 2*4*16*32 (s_q-folded lam_c)
constexpr long O_BC    = 21728;    // 2*4*32 (t_q-folded lam_c bias)
constexpr long O_LAMCP = 21984;    // 2*216*512 lam_c partials
constexpr long O_Q     = 243168;   // u32[2][32][NPOS] bf16-pairs
constexpr long O_K     = 7321056;  // f32[2][16][NPOS]
constexpr long O_V     = 10860000; // u32[2][16][NPOS] bf16-pairs
// total ~57.6 MB

__device__ inline unsigned short f2bf(float f) {
    unsigned int u = __float_as_uint(f);
    u += 0x7FFFu + ((u >> 16) & 1u);   // RNE
    return (unsigned short)(u >> 16);
}
__device__ inline float bflo(unsigned int u) { return __uint_as_float(u << 16); }
__device__ inline float bfhi(unsigned int u) { return __uint_as_float(u & 0xFFFF0000u); }
__device__ inline unsigned int cvtpk(float a, float b) {
    unsigned int r;
    asm("v_cvt_pk_bf16_f32 %0, %1, %2" : "=v"(r) : "v"(a), "v"(b));
    return r;
}
__device__ inline void pkfma(f32x2& c, f32x2 a, f32x2 b) {
    asm("v_pk_fma_f32 %0, %1, %2, %0" : "+v"(c) : "v"(a), "v"(b));
}

// DPP row reductions (VALU pipe, no LDS): lane 15 of each 16-lane row gets the result.
template<int CTRL>
__device__ inline float dpp_shr(float x) {
    int xi = __builtin_bit_cast(int, x);
    return __builtin_bit_cast(float, __builtin_amdgcn_update_dpp(xi, xi, CTRL, 0xf, 0xf, false));
}
__device__ inline float dpp_sum16(float x) {
    x += dpp_shr<0x111>(x);
    x += dpp_shr<0x112>(x);
    x += dpp_shr<0x114>(x);
    x += dpp_shr<0x118>(x);
    return x;
}
__device__ inline float dpp_max16(float x) {
    x = fmaxf(x, dpp_shr<0x111>(x));
    x = fmaxf(x, dpp_shr<0x112>(x));
    x = fmaxf(x, dpp_shr<0x114>(x));
    x = fmaxf(x, dpp_shr<0x118>(x));
    return x;
}

// ---------------- setup: bf16 weights [oc][c] + wposT ----------------
__global__ __launch_bounds__(256) void ksetup(const float* Wq, const float* Wk, const float* Wv,
                                              const float* Wpos, float* ws) {
    int i = blockIdx.x * 256 + threadIdx.x;
    if (i < 7168) {
        int oc = i >> 6, cp = i & 63;
        int c = 2 * cp;
        float v0, v1;
        if (oc < 64)      { v0 = Wq[oc * 128 + c];        v1 = Wq[oc * 128 + c + 1]; }
        else if (oc < 80) { v0 = Wk[(oc - 64) * 128 + c]; v1 = Wk[(oc - 64) * 128 + c + 1]; }
        else              { v0 = Wv[(oc - 80) * 128 + c]; v1 = Wv[(oc - 80) * 128 + c + 1]; }
        ((unsigned int*)(ws + O_WB))[i] = (unsigned int)f2bf(v0) | ((unsigned int)f2bf(v1) << 16);
    } else if (i < 7600) {
        int j = i - 7168;
        int o = j >> 4, k = j & 15;
        ws[O_WPT + j] = Wpos[k * 27 + o];   // o = od*9+oh*3+ow
    }
}

// ---------------- projection via MFMA + fused stat partials (DPP reduce) ----------------
__global__ __launch_bounds__(256, 4) void kproj(const float* __restrict__ x, const float* __restrict__ ws,
                                                unsigned int* __restrict__ qu, float* __restrict__ kr,
                                                unsigned int* __restrict__ vu,
                                                float* __restrict__ PS, float* __restrict__ PQ,
                                                float* __restrict__ PM) {
    __shared__ unsigned int xsu[64 * 68];   // [pos][c-pair] bf16, row = 272 B (16B aligned)
    __shared__ float pss[4 * 112], psq[4 * 112], pmx[4 * 16];
    const unsigned short* WBu = (const unsigned short*)(ws + O_WB);

    int blk0 = blockIdx.x;                // XCD-aware bijective swizzle (grid 3456 = 8*432)
    int blk = (blk0 & 7) * 432 + (blk0 >> 3);
    int b = blk / 1728, tile = blk - b * 1728;
    long base = (long)b * 128 * NPOS + (long)tile * 64;
    int tid = threadIdx.x;

    // stage x tile transposed to [pos][c] bf16; b128 writes (4 iters)
    for (int i = tid; i < 1024; i += 256) {
        int cc = i >> 6, p = i & 63;      // cc: group of 8 channels
        const float* xp = x + base + (long)(8 * cc) * NPOS + p;
        uint4 w;
        w.x = cvtpk(xp[0],               xp[(long)NPOS]);
        w.y = cvtpk(xp[2 * (long)NPOS],  xp[3 * (long)NPOS]);
        w.z = cvtpk(xp[4 * (long)NPOS],  xp[5 * (long)NPOS]);
        w.w = cvtpk(xp[6 * (long)NPOS],  xp[7 * (long)NPOS]);
        *(uint4*)(xsu + p * 68 + cc * 4) = w;
    }
    __syncthreads();

    int lane = tid & 63;
    int wv = __builtin_amdgcn_readfirstlane(tid >> 6);
    int r = lane & 15, g = lane >> 4;

    f32x4 acc[7];
#pragma unroll
    for (int t = 0; t < 7; ++t) acc[t] = (f32x4){0.f, 0.f, 0.f, 0.f};

    const unsigned short* xrow = (const unsigned short*)xsu + (wv * 16 + r) * 136;
#pragma unroll
    for (int ks = 0; ks < 4; ++ks) {
        bf16x8 bfrag = *(const bf16x8*)(const void*)(xrow + ks * 32 + g * 8);
#pragma unroll
        for (int t = 0; t < 7; ++t) {
            bf16x8 afrag = *(const bf16x8*)(const void*)(WBu + (t * 16 + r) * 128 + ks * 32 + g * 8);
            acc[t] = __builtin_amdgcn_mfma_f32_16x16x32_bf16(afrag, bfrag, acc[t], 0, 0, 0);
        }
    }

    long pos = (long)tile * 64 + wv * 16 + r;
    // q (t 0..3): bf16-pair u32
#pragma unroll
    for (int t = 0; t < 4; ++t)
#pragma unroll
        for (int jp = 0; jp < 2; ++jp)
            qu[((long)b * 32 + t * 8 + g * 2 + jp) * NPOS + pos] = cvtpk(acc[t][2 * jp], acc[t][2 * jp + 1]);
    // k (t=4): fp32
#pragma unroll
    for (int j = 0; j < 4; ++j)
        kr[((long)b * 16 + g * 4 + j) * NPOS + pos] = acc[4][j];
    // v (t 5..6): bf16-pair u32
#pragma unroll
    for (int t = 5; t < 7; ++t)
#pragma unroll
        for (int jp = 0; jp < 2; ++jp)
            vu[((long)b * 16 + (t - 5) * 8 + g * 2 + jp) * NPOS + pos] = cvtpk(acc[t][2 * jp], acc[t][2 * jp + 1]);

    // fused stat partials via DPP (VALU pipe); row result lands in lane r==15
#pragma unroll
    for (int t = 0; t < 7; ++t) {
#pragma unroll
        for (int j = 0; j < 4; ++j) {
            float v = acc[t][j];
            float s = dpp_sum16(v);
            float q = dpp_sum16(v * v);
            if (r == 15) {
                int oc = t * 16 + g * 4 + j;
                pss[wv * 112 + oc] = s;
                psq[wv * 112 + oc] = q;
            }
        }
    }
#pragma unroll
    for (int j = 0; j < 4; ++j) {
        float m = dpp_max16(acc[4][j]);
        if (r == 15) pmx[wv * 16 + g * 4 + j] = m;
    }
    __syncthreads();
    if (tid < 112) {
        float s = pss[tid] + pss[112 + tid] + pss[224 + tid] + pss[336 + tid];
        float q = psq[tid] + psq[112 + tid] + psq[224 + tid] + psq[336 + tid];
        PS[(long)blk * 112 + tid] = s;
        PQ[(long)blk * 112 + tid] = q;
    } else if (tid < 128) {
        int kk = tid - 112;
        PM[(long)blk * 16 + kk] = fmaxf(fmaxf(pmx[kk], pmx[16 + kk]),
                                        fmaxf(pmx[32 + kk], pmx[48 + kk]));
    }
}

// ---------------- reduce partials: BN scale/shift + k rowmax ----------------
__global__ __launch_bounds__(256) void kred(const float* __restrict__ PS, const float* __restrict__ PQ,
                                            const float* __restrict__ PM,
                                            const float* gq, const float* bq,
                                            const float* gv, const float* bv, float* ws) {
    __shared__ float rs[256], rq[256];
    int bid = blockIdx.x, tid = threadIdx.x;
    if (bid < 96) {
        int c = bid;
        int oc = c < 64 ? c : c + 16;
        float s = 0.f, q = 0.f;
        for (int i = tid; i < 3456; i += 256) {
            s += PS[(long)i * 112 + oc];
            q += PQ[(long)i * 112 + oc];
        }
        rs[tid] = s; rq[tid] = q;
        __syncthreads();
        for (int st = 128; st > 0; st >>= 1) {
            if (tid < st) { rs[tid] += rs[tid + st]; rq[tid] += rq[tid + st]; }
            __syncthreads();
        }
        if (tid == 0) {
            const float inv_n = 1.f / 221184.f;
            float mean = rs[0] * inv_n;
            float var = rq[0] * inv_n - mean * mean;
            float g = c < 64 ? gq[c] : gv[c - 64];
            float bb = c < 64 ? bq[c] : bv[c - 64];
            float sc = g * rsqrtf(var + EPS);
            ws[O_SARR + c] = sc;
            ws[O_TARR + c] = bb - mean * sc;
        }
    } else {
        int row = bid - 96;
        int b = row >> 4, kk = row & 15;
        float m = -1e30f;
        for (int i = tid; i < 1728; i += 256) m = fmaxf(m, PM[((long)b * 1728 + i) * 16 + kk]);
        rs[tid] = m;
        __syncthreads();
        for (int st = 128; st > 0; st >>= 1) {
            if (tid < st) rs[tid] = fmaxf(rs[tid], rs[tid + st]);
            __syncthreads();
        }
        if (tid == 0) ws[O_RMAX + row] = rs[0];
    }
}

// ---------------- lam_c partials + softmax Z partials ----------------
__global__ __launch_bounds__(256) void klamcp(const float* __restrict__ kr, const unsigned int* __restrict__ vu,
                                              float* __restrict__ ws, float* __restrict__ lamcp) {
    __shared__ float es[16 * 512];
    const float* rmax = ws + O_RMAX;
    int bid = blockIdx.x;                  // 0..431
    int b = bid / 216, chunk = bid - b * 216;
    long p0 = (long)chunk * 512;
    int tid = threadIdx.x;
    // float4 staging of k (p0 is 512-aligned; row bases 16B-aligned)
    for (int i = tid; i < 2048; i += 256) {
        int rr = i >> 7, p4 = (i & 127) << 2;
        float4 kv = *(const float4*)(kr + ((long)b * 16 + rr) * NPOS + p0 + p4);
        float rm = rmax[b * 16 + rr];
        es[rr * 512 + p4 + 0] = expf(kv.x - rm);
        es[rr * 512 + p4 + 1] = expf(kv.y - rm);
        es[rr * 512 + p4 + 2] = expf(kv.z - rm);
        es[rr * 512 + p4 + 3] = expf(kv.w - rm);
    }
    __syncthreads();
    int vp = tid >> 4, pl = tid & 15;
    const unsigned int* vpp = vu + ((long)b * 16 + vp) * NPOS + p0;
    float acc0[16], acc1[16];
#pragma unroll
    for (int k = 0; k < 16; ++k) { acc0[k] = 0.f; acc1[k] = 0.f; }
    for (int j = 0; j < 32; ++j) {
        int p = pl + 16 * j;
        unsigned int u = vpp[p];
        float v0 = bflo(u), v1 = bfhi(u);
#pragma unroll
        for (int k = 0; k < 16; ++k) {
            float e = es[k * 512 + p];
            acc0[k] = fmaf(e, v0, acc0[k]);
            acc1[k] = fmaf(e, v1, acc1[k]);
        }
    }
#pragma unroll
    for (int m = 1; m < 16; m <<= 1) {
#pragma unroll
        for (int k = 0; k < 16; ++k) {
            acc0[k] += __shfl_xor(acc0[k], m, 64);
            acc1[k] += __shfl_xor(acc1[k], m, 64);
        }
    }
    if (pl == 0) {
        long base = (long)bid * 512;
#pragma unroll
        for (int k = 0; k < 16; ++k) {
            lamcp[base + k * 32 + 2 * vp]     = acc0[k];
            lamcp[base + k * 32 + 2 * vp + 1] = acc1[k];
        }
    }
    {
        int rr = tid >> 4, j = tid & 15;
        float s = 0.f;
        const float* er = es + rr * 512 + j * 32;
#pragma unroll 8
        for (int i = 0; i < 32; ++i) s += er[i];
#pragma unroll
        for (int m = 1; m < 16; m <<= 1) s += __shfl_xor(s, m, 64);
        if (j == 0) ws[O_ZP + (long)bid * 16 + rr] = s;
    }
}

// ---------------- fold: RZI + SW/CW + lam_c reduce + q-BN fold (fused) ----------------
// 2 blocks (one per batch) x 512 threads
__global__ __launch_bounds__(512) void kfold(float* ws) {
    __shared__ float lamlds[512];
    int b = blockIdx.x, tid = threadIdx.x;
    const float* lamcp = ws + O_LAMCP;

    // per-thread lam_c partial sum over chunks (same order as before: c=0..215)
    float S = 0.f;
    for (int c = 0; c < 216; ++c) S += lamcp[((long)b * 216 + c) * 512 + tid];

    // softmax Z finalize (16 rows of this batch)
    if (tid < 16) {
        float z = 0.f;
        for (int c = 0; c < 216; ++c) z += ws[O_ZP + ((long)b * 216 + c) * 16 + tid];
        ws[O_RZI + b * 16 + tid] = 1.f / z;
    }
    // SW/CW (batch-independent): block 0 only
    if (b == 0) {
        for (int i = tid; i < 1728; i += 512) {
            int h = i / 432, r = i - h * 432, o = r >> 4, k = r & 15;
            ws[O_SW + i] = ws[O_SARR + h * 16 + k] * ws[O_WPT + o * 16 + k];
        }
        if (tid < 108) {
            int h = tid / 27, o = tid - h * 27;
            float s = 0.f;
            for (int k = 0; k < 16; ++k) s += ws[O_TARR + h * 16 + k] * ws[O_WPT + o * 16 + k];
            ws[O_CW + tid] = s;
        }
    }
    __syncthreads();

    // lam_c finalize (BN-v + 1/Z fold), kept in LDS
    {
        int kk = tid >> 5, v = tid & 31;
        float sv = ws[O_SARR + 64 + v], tv = ws[O_TARR + 64 + v];
        lamlds[tid] = sv * S * ws[O_RZI + b * 16 + kk] + tv;
    }
    __syncthreads();

    // LAMC2[b][h][k][v] = s_q[h*16+k] * lam_c[k*32+v]
    for (int r = tid; r < 2048; r += 512) {
        int h = r >> 9, k = (r >> 5) & 15;
        ws[O_LAMC2 + (long)b * 2048 + r] = ws[O_SARR + h * 16 + k] * lamlds[r & 511];
    }
    // BC[b][h][v] = sum_k t_q[h*16+k] * lam_c[k*32+v]
    if (tid < 128) {
        int h = tid >> 5, v = tid & 31;
        float s = 0.f;
#pragma unroll
        for (int k = 0; k < 16; ++k) s += ws[O_TARR + h * 16 + k] * lamlds[k * 32 + v];
        ws[O_BC + b * 128 + tid] = s;
    }
}

// ---------------- final fused kernel ----------------
// tile (d,h,w) = (2,4,16) = 128 pos, 512 threads (8 waves), halo z = 0..431
__global__ __launch_bounds__(512, 4) void kfinal(const unsigned int* __restrict__ qu,
                                                 const unsigned int* __restrict__ vu,
                                                 const float* __restrict__ ws, float* __restrict__ y) {
    __shared__ unsigned int vbnu[432 * 16];      // [z][8 slots x 16B], swz sl^=((z^(z>>2))&3)
    __shared__ unsigned short qwh[27 * 128 * 4]; // [o][pos][h] bf16
    __shared__ unsigned int qsu[128 * 32];       // [pos][8 slots x 16B], swz sl^=(pos&7)
    const float* sarr  = ws + O_SARR;
    const float* tarr  = ws + O_TARR;
    const float* swp   = ws + O_SW;
    const float* cwp   = ws + O_CW;
    const float* lamc2 = ws + O_LAMC2;
    const float* bcp   = ws + O_BC;

    int bid0 = blockIdx.x;                    // XCD-aware bijective swizzle (grid 1728 = 8*216)
    int bid = (bid0 & 7) * 216 + (bid0 >> 3);
    int b = bid / 864, t = bid - b * 864;     // tiles: d 24 x h 12 x w 3
    int td = t / 36, r = t - td * 36;
    int th = r / 3, tw = r - th * 3;
    int d0 = td * 2, h0 = th * 4, w0 = tw * 16;
    int tid = threadIdx.x;

    // phase A: halo load of packed v -> BN -> bf16 pair, swizzled [z][v]
    for (int i = tid; i < 16 * 432; i += 512) {
        int vp = i / 432, z = i - vp * 432;
        int zd = z / 108, rr = z - zd * 108;
        int zh = rr / 18, zw = rr - zh * 18;
        int gd = d0 - 1 + zd, gh = h0 - 1 + zh, gw = w0 - 1 + zw;
        unsigned int out = 0u;
        if ((unsigned)gd < 48u && (unsigned)gh < 48u && (unsigned)gw < 48u) {
            unsigned int u = vu[((long)b * 16 + vp) * NPOS + gd * 2304 + gh * 48 + gw];
            float a = fmaf(bflo(u), sarr[64 + 2 * vp], tarr[64 + 2 * vp]);
            float c = fmaf(bfhi(u), sarr[65 + 2 * vp], tarr[65 + 2 * vp]);
            out = cvtpk(a, c);
        }
        int sl = (vp >> 2) ^ ((z ^ (z >> 2)) & 3);
        vbnu[z * 16 + sl * 4 + (vp & 3)] = out;
    }

    // phase B: qw + q stash
    int lane = tid & 63;
    int wv = __builtin_amdgcn_readfirstlane(tid >> 6);
    int hsel = wv & 3, psel = wv >> 2;
    int pos_l = psel * 64 + lane;
    int lh = lane >> 4, lw = lane & 15;
    int goff = (d0 + psel) * 2304 + (h0 + lh) * 48 + (w0 + lw);
    {
        unsigned int uq[8];
        float qk[16];
        const unsigned int* qb = qu + ((long)b * 32 + hsel * 8) * NPOS + goff;
#pragma unroll
        for (int m = 0; m < 8; ++m) {
            uq[m] = qb[(long)m * NPOS];
            qk[2 * m] = bflo(uq[m]);
            qk[2 * m + 1] = bfhi(uq[m]);
        }
#pragma unroll
        for (int o = 0; o < 27; ++o) {
            float a = cwp[hsel * 27 + o];
            const float* swrow = swp + (hsel * 27 + o) * 16;
#pragma unroll
            for (int k = 0; k < 16; ++k) a = fmaf(qk[k], swrow[k], a);
            qwh[(o * 128 + pos_l) * 4 + hsel] = (unsigned short)cvtpk(a, a);
        }
        uint4 w0v = make_uint4(uq[0], uq[1], uq[2], uq[3]);
        uint4 w1v = make_uint4(uq[4], uq[5], uq[6], uq[7]);
        *(uint4*)(qsu + pos_l * 32 + (((2 * hsel) ^ (pos_l & 7)) << 2)) = w0v;
        *(uint4*)(qsu + pos_l * 32 + (((2 * hsel + 1) ^ (pos_l & 7)) << 2)) = w1v;
    }
    __syncthreads();

    // phase C: (pos_l, v-group vg -> v0..v0+7), all 4 h
    int vg = wv & 3;
    int v0 = vg * 8;
    f32x2 acc2[4][4];
#pragma unroll
    for (int hh = 0; hh < 4; ++hh)
#pragma unroll
        for (int p = 0; p < 4; ++p) {
            acc2[hh][p][0] = bcp[(b * 4 + hh) * 32 + v0 + 2 * p];
            acc2[hh][p][1] = bcp[(b * 4 + hh) * 32 + v0 + 2 * p + 1];
        }

    // y_c: q (bf16 from LDS) x s_q-folded lam_c (scalar fmaf — compiler schedules best)
#pragma unroll
    for (int s = 0; s < 8; ++s) {
        uint4 uq = *(const uint4*)(qsu + pos_l * 32 + ((s ^ (pos_l & 7)) << 2));
        int hh = s >> 1, k0 = (s & 1) * 8;
        float qa[8];
        qa[0] = bflo(uq.x); qa[1] = bfhi(uq.x);
        qa[2] = bflo(uq.y); qa[3] = bfhi(uq.y);
        qa[4] = bflo(uq.z); qa[5] = bfhi(uq.z);
        qa[6] = bflo(uq.w); qa[7] = bfhi(uq.w);
#pragma unroll
        for (int j = 0; j < 8; ++j) {
            const float* l2 = lamc2 + (((b * 4 + hh) * 16 + k0 + j) << 5) + v0;
#pragma unroll
            for (int p = 0; p < 4; ++p) {
                acc2[hh][p][0] = fmaf(qa[j], l2[2 * p], acc2[hh][p][0]);
                acc2[hh][p][1] = fmaf(qa[j], l2[2 * p + 1], acc2[hh][p][1]);
            }
        }
    }

    // y_p: 27-point stencil with packed-fp32 FMA
    int zb = psel * 108 + lh * 18 + lw;
#pragma unroll
    for (int od = 0; od < 3; ++od)
#pragma unroll
    for (int oh = 0; oh < 3; ++oh)
#pragma unroll
    for (int ow = 0; ow < 3; ++ow) {
        int o = od * 9 + oh * 3 + ow;
        int z = zb + od * 108 + oh * 18 + ow;
        int sl = vg ^ ((z ^ (z >> 2)) & 3);
        uint4 u = *(const uint4*)(vbnu + z * 16 + (sl << 2));
        uint2 uqw = *(const uint2*)(qwh + ((o * 128 + pos_l) << 2));
        f32x2 s0; s0[0] = bflo(u.x); s0[1] = bfhi(u.x);
        f32x2 s1; s1[0] = bflo(u.y); s1[1] = bfhi(u.y);
        f32x2 s2; s2[0] = bflo(u.z); s2[1] = bfhi(u.z);
        f32x2 s3; s3[0] = bflo(u.w); s3[1] = bfhi(u.w);
        float q0 = bflo(uqw.x), q1 = bfhi(uqw.x);
        float q2 = bflo(uqw.y), q3 = bfhi(uqw.y);
        f32x2 qd0; qd0[0] = q0; qd0[1] = q0;
        f32x2 qd1; qd1[0] = q1; qd1[1] = q1;
        f32x2 qd2; qd2[0] = q2; qd2[1] = q2;
        f32x2 qd3; qd3[0] = q3; qd3[1] = q3;
        pkfma(acc2[0][0], qd0, s0); pkfma(acc2[0][1], qd0, s1);
        pkfma(acc2[0][2], qd0, s2); pkfma(acc2[0][3], qd0, s3);
        pkfma(acc2[1][0], qd1, s0); pkfma(acc2[1][1], qd1, s1);
        pkfma(acc2[1][2], qd1, s2); pkfma(acc2[1][3], qd1, s3);
        pkfma(acc2[2][0], qd2, s0); pkfma(acc2[2][1], qd2, s1);
        pkfma(acc2[2][2], qd2, s2); pkfma(acc2[2][3], qd2, s3);
        pkfma(acc2[3][0], qd3, s0); pkfma(acc2[3][1], qd3, s1);
        pkfma(acc2[3][2], qd3, s2); pkfma(acc2[3][3], qd3, s3);
    }

    long pbase = (long)b * 128 * NPOS + goff;
#pragma unroll
    for (int hh = 0; hh < 4; ++hh)
#pragma unroll
        for (int p = 0; p < 4; ++p) {
            y[pbase + (long)(hh * 32 + v0 + 2 * p) * NPOS]     = acc2[hh][p][0];
            y[pbase + (long)(hh * 32 + v0 + 2 * p + 1) * NPOS] = acc2[hh][p][1];
        }
}

extern "C" void kernel_launch(void* const* d_in, const int* in_sizes, int n_in,
                              void* d_out, int out_size, void* d_ws, size_t ws_size,
                              hipStream_t stream) {
    const float* x    = (const float*)d_in[0];
    const float* Wq   = (const float*)d_in[1];
    const float* Wk   = (const float*)d_in[2];
    const float* Wv   = (const float*)d_in[3];
    const float* Wpos = (const float*)d_in[4];
    const float* gq   = (const float*)d_in[5];
    const float* bq   = (const float*)d_in[6];
    const float* gv   = (const float*)d_in[7];
    const float* bv   = (const float*)d_in[8];
    float* ws = (float*)d_ws;
    float* y  = (float*)d_out;
    unsigned int* qu = (unsigned int*)(ws + O_Q);
    float*        kr = ws + O_K;
    unsigned int* vu = (unsigned int*)(ws + O_V);
    // partial-sum scratch inside d_out (fully overwritten by kfinal afterwards)
    float* PS = y;                 // [3456][112]
    float* PQ = y + 387072;        // [3456][112]
    float* PM = y + 774144;        // [3456][16]

    ksetup <<<30,   256, 0, stream>>>(Wq, Wk, Wv, Wpos, ws);
    kproj  <<<3456, 256, 0, stream>>>(x, ws, qu, kr, vu, PS, PQ, PM);
    kred   <<<128,  256, 0, stream>>>(PS, PQ, PM, gq, bq, gv, bv, ws);
    klamcp <<<432,  256, 0, stream>>>(kr, vu, ws, ws + O_LAMCP);
    kfold  <<<2,    512, 0, stream>>>(ws);
    kfinal <<<1728, 512, 0, stream>>>(qu, vu, ws, y);
}